// Round 13
// baseline (570.712 us; speedup 1.0000x reference)
//
#include <hip/hip_runtime.h>
#include <hip/hip_bf16.h>
#include <math.h>

typedef unsigned short u16;
typedef __attribute__((ext_vector_type(8))) short bf16x8;
typedef __attribute__((ext_vector_type(4))) float f32x4;

#define Bb 16
#define Cch 512
#define Ss 1024
#define NHh 8
#define DHh 64
#define CPG 64
#define EPSV 1e-5f
#define R_TOTAL (Bb*Ss)   // 16384

__device__ inline u16 f2bf(float f) {
    unsigned int u = __float_as_uint(f);
    unsigned int r = (u + 0x7fffu + ((u >> 16) & 1u)) >> 16;
    return (u16)r;
}

// async global->LDS, 16B per lane, dest = wave-uniform base + lane*16
__device__ inline void gld16(const u16* g, u16* l) {
    __builtin_amdgcn_global_load_lds(
        (const __attribute__((address_space(1))) void*)g,
        (__attribute__((address_space(3))) void*)l,
        16, 0, 0);
}

// ---------------- GroupNorm stats ----------------
__global__ __launch_bounds__(256) void gn_stats(const float* __restrict__ x,
                                                float* __restrict__ stats) {
    int bg = blockIdx.x;
    int b = bg >> 3, g = bg & 7;
    const float* base = x + ((size_t)b * Cch + (size_t)g * CPG) * Ss;
    float s = 0.f, ss = 0.f;
    for (int i = threadIdx.x; i < CPG * Ss; i += 256) {
        float v = base[i];
        s += v; ss += v * v;
    }
    for (int o = 32; o > 0; o >>= 1) { s += __shfl_down(s, o); ss += __shfl_down(ss, o); }
    __shared__ float red[2][4];
    int wid = threadIdx.x >> 6, lane = threadIdx.x & 63;
    if (lane == 0) { red[0][wid] = s; red[1][wid] = ss; }
    __syncthreads();
    if (threadIdx.x == 0) {
        float S1 = red[0][0] + red[0][1] + red[0][2] + red[0][3];
        float S2 = red[1][0] + red[1][1] + red[1][2] + red[1][3];
        const float inv_n = 1.0f / (CPG * Ss);
        float mu = S1 * inv_n;
        float var = S2 * inv_n - mu * mu;
        stats[bg * 2]     = mu;
        stats[bg * 2 + 1] = rsqrtf(var + EPSV);
    }
}

// ---------------- GroupNorm apply + transpose -> bf16 (B,S,C) ----------------
__global__ __launch_bounds__(256) void gn_apply_t_bf(const float* __restrict__ x,
                                                     const float* __restrict__ stats,
                                                     const float* __restrict__ gw,
                                                     const float* __restrict__ gb,
                                                     u16* __restrict__ ht) {
    __shared__ float tile[32][33];
    int b  = blockIdx.z;
    int c0 = blockIdx.y * 32;
    int s0 = blockIdx.x * 32;
    int tx = threadIdx.x, ty = threadIdx.y;
#pragma unroll
    for (int i = 0; i < 4; i++) {
        int c = c0 + ty + i * 8;
        int g = c >> 6;
        float mu = stats[(b * 8 + g) * 2];
        float rs = stats[(b * 8 + g) * 2 + 1];
        float v = x[((size_t)b * Cch + c) * Ss + s0 + tx];
        tile[ty + i * 8][tx] = (v - mu) * rs * gw[c] + gb[c];
    }
    __syncthreads();
#pragma unroll
    for (int i = 0; i < 4; i++) {
        int s = s0 + ty + i * 8;
        ht[((size_t)b * Ss + s) * Cch + c0 + tx] = f2bf(tile[tx][ty + i * 8]);
    }
}

// ---------------- fp32 -> bf16 straight convert ----------------
__global__ __launch_bounds__(256) void conv_bf16(const float* __restrict__ in,
                                                 u16* __restrict__ outp, int n) {
    for (int i = blockIdx.x * 256 + threadIdx.x; i < n; i += gridDim.x * 256)
        outp[i] = f2bf(in[i]);
}

// ---------------- transpose + convert: in (R x C) fp32 -> out (C x R) bf16 ----------------
__global__ __launch_bounds__(256) void convT_bf16(const float* __restrict__ in,
                                                  u16* __restrict__ outp, int R, int C) {
    __shared__ float tile[32][33];
    int c0 = blockIdx.x * 32, r0 = blockIdx.y * 32;
    int tx = threadIdx.x, ty = threadIdx.y;
#pragma unroll
    for (int i = 0; i < 4; i++)
        tile[ty + i * 8][tx] = in[(size_t)(r0 + ty + i * 8) * C + c0 + tx];
    __syncthreads();
#pragma unroll
    for (int i = 0; i < 4; i++)
        outp[(size_t)(c0 + ty + i * 8) * R + r0 + tx] = f2bf(tile[tx][ty + i * 8]);
}

// ---------------- per-head V transpose: vb [b][s][512] -> vt [(b*8+h)][64][1024] ----------
__global__ __launch_bounds__(256) void vtrans(const u16* __restrict__ in,
                                              u16* __restrict__ outp) {
    __shared__ u16 tile[64][66];
    int s0 = blockIdx.x * 64, h = blockIdx.y, b = blockIdx.z;
    const u16* src = in + ((size_t)b * Ss + s0) * Cch + h * 64;
    int r = threadIdx.x >> 3, c8 = (threadIdx.x & 7) * 8;
#pragma unroll
    for (int p = 0; p < 2; p++) {
        int rr = r + p * 32;
        *(int4*)&tile[rr][c8] = *(const int4*)&src[(size_t)rr * Cch + c8];
    }
    __syncthreads();
    u16* dst = outp + ((size_t)(b * 8 + h) * 64) * Ss + s0;
#pragma unroll
    for (int p = 0; p < 2; p++) {
        int d = r + p * 32;
        u16 vals[8];
#pragma unroll
        for (int e = 0; e < 8; e++) vals[e] = tile[c8 + e][d];
        *(int4*)&dst[(size_t)d * Ss + c8] = *(int4*)vals;
    }
}

// ---------------- LayerNorm rows (fp32 in, bf16 out) ----------------
__global__ __launch_bounds__(256) void layer_norm_rows_bf(const float* __restrict__ in,
                                                          const float* __restrict__ w,
                                                          const float* __restrict__ bb,
                                                          u16* __restrict__ outp) {
    int row = blockIdx.x;
    const float* p = in + (size_t)row * Cch;
    float v0 = p[threadIdx.x], v1 = p[threadIdx.x + 256];
    float s = v0 + v1, ss = v0 * v0 + v1 * v1;
    for (int o = 32; o > 0; o >>= 1) { s += __shfl_down(s, o); ss += __shfl_down(ss, o); }
    __shared__ float red[2][4];
    __shared__ float mu_s, rs_s;
    int wid = threadIdx.x >> 6, lane = threadIdx.x & 63;
    if (lane == 0) { red[0][wid] = s; red[1][wid] = ss; }
    __syncthreads();
    if (threadIdx.x == 0) {
        float S1 = red[0][0] + red[0][1] + red[0][2] + red[0][3];
        float S2 = red[1][0] + red[1][1] + red[1][2] + red[1][3];
        float mu = S1 * (1.0f / Cch);
        float var = S2 * (1.0f / Cch) - mu * mu;
        mu_s = mu; rs_s = rsqrtf(var + EPSV);
    }
    __syncthreads();
    float mu = mu_s, rs = rs_s;
    outp[(size_t)row * Cch + threadIdx.x]       = f2bf((v0 - mu) * rs * w[threadIdx.x] + bb[threadIdx.x]);
    outp[(size_t)row * Cch + threadIdx.x + 256] = f2bf((v1 - mu) * rs * w[threadIdx.x + 256] + bb[threadIdx.x + 256]);
}

// ---------------- MFMA GEMM: out(MxN) = A(MxK bf16) @ Bt(NxK bf16)^T ----------------
// 128x128 tile, BK=32, 256 thr = 4 waves (2x2). Staging via global_load_lds width-16:
// wave-uniform LDS base + lane*16B; lane l covers row=wave*32+i*16+(l>>2), k=(l&3)*8.
// EPI: 0 = store bf16; 1 = fp32 +bias; 2 = fp32 +bias+res(inplace); 3 = EPI2 + bf16 copy.
template<int EPI>
__global__ __launch_bounds__(256) void mfma_gemm(const u16* __restrict__ A,
                                                 const u16* __restrict__ Bt,
                                                 const float* __restrict__ bias,
                                                 float* __restrict__ fout,
                                                 u16* __restrict__ outb,
                                                 int K, int N) {
    __shared__ u16 As[128 * 32];
    __shared__ u16 Bs[128 * 32];
    int tid = threadIdx.x;
    int m0 = blockIdx.y * 128, n0 = blockIdx.x * 128;
    int wave = tid >> 6, lane = tid & 63;
    int wr = wave >> 1, wc = wave & 1;
    int l15 = lane & 15, l4 = lane >> 4;

    f32x4 zero4 = {0.f, 0.f, 0.f, 0.f};
    f32x4 acc[4][4];
#pragma unroll
    for (int i = 0; i < 4; i++)
#pragma unroll
        for (int j = 0; j < 4; j++) acc[i][j] = zero4;

    int gr = lane >> 2, gk = (lane & 3) * 8;
    const u16* ga = A  + (size_t)(m0 + wave * 32 + gr) * K + gk;
    const u16* gb = Bt + (size_t)(n0 + wave * 32 + gr) * K + gk;
    u16* lA0 = As + wave * 1024;           // bytes: wave*2048
    u16* lA1 = As + wave * 1024 + 512;     // +1024 bytes
    u16* lB0 = Bs + wave * 1024;
    u16* lB1 = Bs + wave * 1024 + 512;

    for (int kt = 0; kt < K; kt += 32) {
        __syncthreads();                    // prev-tile reads done
        gld16(ga + kt,                 lA0);
        gld16(ga + (size_t)16 * K + kt, lA1);
        gld16(gb + kt,                 lB0);
        gld16(gb + (size_t)16 * K + kt, lB1);
        __syncthreads();                    // drains vmcnt -> tile ready
        bf16x8 af[4], bfr[4];
#pragma unroll
        for (int mi = 0; mi < 4; mi++)
            af[mi] = *(const bf16x8*)&As[(wr * 64 + mi * 16 + l15) * 32 + l4 * 8];
#pragma unroll
        for (int nj = 0; nj < 4; nj++)
            bfr[nj] = *(const bf16x8*)&Bs[(wc * 64 + nj * 16 + l15) * 32 + l4 * 8];
#pragma unroll
        for (int mi = 0; mi < 4; mi++)
#pragma unroll
            for (int nj = 0; nj < 4; nj++)
                acc[mi][nj] = __builtin_amdgcn_mfma_f32_16x16x32_bf16(af[mi], bfr[nj], acc[mi][nj], 0, 0, 0);
    }

#pragma unroll
    for (int mi = 0; mi < 4; mi++)
#pragma unroll
        for (int nj = 0; nj < 4; nj++)
#pragma unroll
            for (int r = 0; r < 4; r++) {
                int row = m0 + wr * 64 + mi * 16 + l4 * 4 + r;
                int col = n0 + wc * 64 + nj * 16 + l15;
                float v = acc[mi][nj][r];
                if constexpr (EPI == 0) {
                    outb[(size_t)row * N + col] = f2bf(v);
                } else {
                    v += bias[col];
                    if constexpr (EPI >= 2) v += fout[(size_t)row * N + col];
                    fout[(size_t)row * N + col] = v;
                    if constexpr (EPI == 3) outb[(size_t)row * N + col] = f2bf(v);
                }
            }
}

// ---------------- GEGLU MFMA: both halves of tn3 @ wg, fused exact GELU, bf16 out --------
__global__ __launch_bounds__(256) void geglu_mfma(const u16* __restrict__ A,
                                                  const u16* __restrict__ WgT,  // [4096][512]
                                                  const float* __restrict__ bg,
                                                  u16* __restrict__ ag) {
    __shared__ u16 As[128 * 32];
    __shared__ u16 Bs1[64 * 32];
    __shared__ u16 Bs2[64 * 32];
    const int K = 512;
    int tid = threadIdx.x;
    int m0 = blockIdx.y * 128, n0 = blockIdx.x * 64;
    int wave = tid >> 6, lane = tid & 63;
    int wr = wave >> 1, wc = wave & 1;
    int l15 = lane & 15, l4 = lane >> 4;

    f32x4 zero4 = {0.f, 0.f, 0.f, 0.f};
    f32x4 accA[4][2], accG[4][2];
#pragma unroll
    for (int i = 0; i < 4; i++) { accA[i][0] = zero4; accA[i][1] = zero4; accG[i][0] = zero4; accG[i][1] = zero4; }

    int gr = lane >> 2, gk = (lane & 3) * 8;
    const u16* ga  = A   + (size_t)(m0 + wave * 32 + gr) * K + gk;
    const u16* gb1 = WgT + (size_t)(n0 + wave * 16 + gr) * K + gk;
    const u16* gb2 = WgT + (size_t)(2048 + n0 + wave * 16 + gr) * K + gk;
    u16* lA0 = As  + wave * 1024;
    u16* lA1 = As  + wave * 1024 + 512;
    u16* lB1 = Bs1 + wave * 512;           // bytes: wave*1024
    u16* lB2 = Bs2 + wave * 512;

    for (int kt = 0; kt < K; kt += 32) {
        __syncthreads();
        gld16(ga + kt,                 lA0);
        gld16(ga + (size_t)16 * K + kt, lA1);
        gld16(gb1 + kt,                lB1);
        gld16(gb2 + kt,                lB2);
        __syncthreads();
        bf16x8 af[4], b1[2], b2[2];
#pragma unroll
        for (int mi = 0; mi < 4; mi++)
            af[mi] = *(const bf16x8*)&As[(wr * 64 + mi * 16 + l15) * 32 + l4 * 8];
#pragma unroll
        for (int nj = 0; nj < 2; nj++) {
            b1[nj] = *(const bf16x8*)&Bs1[(wc * 32 + nj * 16 + l15) * 32 + l4 * 8];
            b2[nj] = *(const bf16x8*)&Bs2[(wc * 32 + nj * 16 + l15) * 32 + l4 * 8];
        }
#pragma unroll
        for (int mi = 0; mi < 4; mi++)
#pragma unroll
            for (int nj = 0; nj < 2; nj++) {
                accA[mi][nj] = __builtin_amdgcn_mfma_f32_16x16x32_bf16(af[mi], b1[nj], accA[mi][nj], 0, 0, 0);
                accG[mi][nj] = __builtin_amdgcn_mfma_f32_16x16x32_bf16(af[mi], b2[nj], accG[mi][nj], 0, 0, 0);
            }
    }

#pragma unroll
    for (int mi = 0; mi < 4; mi++)
#pragma unroll
        for (int nj = 0; nj < 2; nj++)
#pragma unroll
            for (int r = 0; r < 4; r++) {
                int row = m0 + wr * 64 + mi * 16 + l4 * 4 + r;
                int col = n0 + wc * 32 + nj * 16 + l15;
                float a = accA[mi][nj][r] + bg[col];
                float g = accG[mi][nj][r] + bg[2048 + col];
                float ge = 0.5f * g * (1.0f + erff(g * 0.70710678118654752f));
                ag[(size_t)row * 2048 + col] = f2bf(a * ge);
            }
}

// ---------------- MFMA flash attention (softmax in log2 domain) ----------------
__global__ __launch_bounds__(256) void flash_attn_mfma(const u16* __restrict__ q,
                                                       const u16* __restrict__ k,
                                                       const u16* __restrict__ vt,  // [b*8+h][64][1024]
                                                       u16* __restrict__ o) {
    __shared__ u16 Qs[64 * 72];
    __shared__ u16 Ks[64 * 72];
    __shared__ u16 Vt[64 * 72];
    __shared__ u16 Ps[64 * 68];
    const int tid = threadIdx.x;
    const int h = blockIdx.y, b = blockIdx.z;
    const int q0 = blockIdx.x * 64;
    const size_t hb  = (size_t)b * Ss * Cch + (size_t)h * DHh;
    const size_t vhb = ((size_t)(b * NHh + h) * DHh) * Ss;
    const float SCL = 0.125f * 1.44269504089f;   // 1/sqrt(64) * log2(e)

    const int wq = tid >> 6;
    const int lane = tid & 63;
    const int l15 = lane & 15, l4 = lane >> 4;

    {
        int r = tid >> 2, c4 = (tid & 3) * 16;
        const u16* src = q + hb + (size_t)(q0 + r) * Cch + c4;
        *(int4*)&Qs[r * 72 + c4]     = *(const int4*)src;
        *(int4*)&Qs[r * 72 + c4 + 8] = *(const int4*)(src + 8);
    }

    f32x4 zero4 = {0.f, 0.f, 0.f, 0.f};
    f32x4 oacc[4];
    float m_[4], l_[4];
#pragma unroll
    for (int j = 0; j < 4; j++) oacc[j] = zero4;
#pragma unroll
    for (int r = 0; r < 4; r++) { m_[r] = -1e30f; l_[r] = 0.f; }

    for (int t0 = 0; t0 < Ss; t0 += 64) {
        __syncthreads();
        {
            int r = tid >> 2, c4 = (tid & 3) * 16;
            const u16* ksrc = k + hb + (size_t)(t0 + r) * Cch + c4;
            *(int4*)&Ks[r * 72 + c4]     = *(const int4*)ksrc;
            *(int4*)&Ks[r * 72 + c4 + 8] = *(const int4*)(ksrc + 8);
            const u16* vsrc = vt + vhb + (size_t)r * Ss + t0 + c4;
            *(int4*)&Vt[r * 72 + c4]     = *(const int4*)vsrc;
            *(int4*)&Vt[r * 72 + c4 + 8] = *(const int4*)(vsrc + 8);
        }
        __syncthreads();

        f32x4 sacc[4];
#pragma unroll
        for (int j = 0; j < 4; j++) sacc[j] = zero4;
#pragma unroll
        for (int ks = 0; ks < 2; ks++) {
            bf16x8 aq = *(const bf16x8*)&Qs[(wq * 16 + l15) * 72 + ks * 32 + l4 * 8];
#pragma unroll
            for (int j = 0; j < 4; j++) {
                bf16x8 bk = *(const bf16x8*)&Ks[(j * 16 + l15) * 72 + ks * 32 + l4 * 8];
                sacc[j] = __builtin_amdgcn_mfma_f32_16x16x32_bf16(aq, bk, sacc[j], 0, 0, 0);
            }
        }

#pragma unroll
        for (int r = 0; r < 4; r++) {
            float s0 = sacc[0][r] * SCL;
            float s1 = sacc[1][r] * SCL;
            float s2 = sacc[2][r] * SCL;
            float s3 = sacc[3][r] * SCL;
            float tm = fmaxf(fmaxf(s0, s1), fmaxf(s2, s3));
            tm = fmaxf(tm, __shfl_xor(tm, 1));
            tm = fmaxf(tm, __shfl_xor(tm, 2));
            tm = fmaxf(tm, __shfl_xor(tm, 4));
            tm = fmaxf(tm, __shfl_xor(tm, 8));
            float nm = fmaxf(m_[r], tm);
            float sc = exp2f(m_[r] - nm);
            m_[r] = nm;
            float p0 = exp2f(s0 - nm), p1 = exp2f(s1 - nm);
            float p2 = exp2f(s2 - nm), p3 = exp2f(s3 - nm);
            int prow = (wq * 16 + l4 * 4 + r) * 68 + l15;
            Ps[prow]      = f2bf(p0);
            Ps[prow + 16] = f2bf(p1);
            Ps[prow + 32] = f2bf(p2);
            Ps[prow + 48] = f2bf(p3);
            float rs = p0 + p1 + p2 + p3;
            rs += __shfl_xor(rs, 1);
            rs += __shfl_xor(rs, 2);
            rs += __shfl_xor(rs, 4);
            rs += __shfl_xor(rs, 8);
            l_[r] = l_[r] * sc + rs;
#pragma unroll
            for (int j = 0; j < 4; j++) oacc[j][r] *= sc;
        }

#pragma unroll
        for (int ks = 0; ks < 2; ks++) {
            bf16x8 pa = *(const bf16x8*)&Ps[(wq * 16 + l15) * 68 + ks * 32 + l4 * 8];
#pragma unroll
            for (int j = 0; j < 4; j++) {
                bf16x8 bv = *(const bf16x8*)&Vt[(j * 16 + l15) * 72 + ks * 32 + l4 * 8];
                oacc[j] = __builtin_amdgcn_mfma_f32_16x16x32_bf16(pa, bv, oacc[j], 0, 0, 0);
            }
        }
    }

#pragma unroll
    for (int r = 0; r < 4; r++) {
        float inv = 1.0f / l_[r];
        int orow = (wq * 16 + l4 * 4 + r) * 72 + l15;
#pragma unroll
        for (int j = 0; j < 4; j++)
            Qs[orow + 16 * j] = f2bf(oacc[j][r] * inv);
    }
    __syncthreads();
    {
        int r = tid >> 2, c4 = (tid & 3) * 16;
        u16* dst = o + hb + (size_t)(q0 + r) * Cch + c4;
        *(int4*)dst       = *(const int4*)&Qs[r * 72 + c4];
        *(int4*)(dst + 8) = *(const int4*)&Qs[r * 72 + c4 + 8];
    }
}

// ---------------- final: out(B,C,S) = tmp(B,S,C)^T + x ----------------
__global__ __launch_bounds__(256) void final_out(const float* __restrict__ tmp,
                                                 const float* __restrict__ x,
                                                 float* __restrict__ outp) {
    __shared__ float tile[32][33];
    int b = blockIdx.z, c0 = blockIdx.y * 32, s0 = blockIdx.x * 32;
    int tx = threadIdx.x, ty = threadIdx.y;
#pragma unroll
    for (int i = 0; i < 4; i++) {
        int s = s0 + ty + i * 8;
        tile[ty + i * 8][tx] = tmp[((size_t)b * Ss + s) * Cch + c0 + tx];
    }
    __syncthreads();
#pragma unroll
    for (int i = 0; i < 4; i++) {
        int c = c0 + ty + i * 8;
        size_t idx = ((size_t)b * Cch + c) * Ss + s0 + tx;
        outp[idx] = tile[tx][ty + i * 8] + x[idx];
    }
}

extern "C" void kernel_launch(void* const* d_in, const int* in_sizes, int n_in,
                              void* d_out, int out_size, void* d_ws, size_t ws_size,
                              hipStream_t stream) {
    (void)in_sizes; (void)n_in; (void)out_size; (void)ws_size;
    const float* x      = (const float*)d_in[0];
    const float* gn_w   = (const float*)d_in[1];
    const float* gn_b   = (const float*)d_in[2];
    const float* pin_w  = (const float*)d_in[3];
    const float* pin_b  = (const float*)d_in[4];
    const float* ln1_w  = (const float*)d_in[5];
    const float* ln1_b  = (const float*)d_in[6];
    const float* wq     = (const float*)d_in[7];
    const float* wk     = (const float*)d_in[8];
    const float* wv     = (const float*)d_in[9];
    const float* wo     = (const float*)d_in[10];
    const float* bo     = (const float*)d_in[11];
    const float* ln3_w  = (const float*)d_in[12];
    const float* ln3_b  = (const float*)d_in[13];
    const float* wg     = (const float*)d_in[14];
    const float* bg     = (const float*)d_in[15];
    const float* wd     = (const float*)d_in[16];
    const float* bd     = (const float*)d_in[17];
    const float* pout_w = (const float*)d_in[18];
    const float* pout_b = (const float*)d_in[19];
    float* out = (float*)d_out;

    // ---- workspace layout (bytes) ----
    char* W = (char*)d_ws;
    float* t_f32   = (float*)W;                                   // 33.55 MB
    float* tmp_f32 = (float*)(W + 33554432);                      // 33.55 MB
    u16* qb    = (u16*)(W + 67108864);                            // 16.78 MB
    u16* kb    = qb + 8388608;
    u16* vb    = kb + 8388608;
    u16* attnb = vb + 8388608;
    u16* Xb    = attnb + 8388608;                                 // 16.78 MB
    float* stats = (float*)(W + 67108864 + 5ull * 16777216);      // 1 KB
    u16* wbase = (u16*)(W + 67108864 + 5ull * 16777216 + 1024);
    u16* pinB  = wbase;                 // 512*512  (already [N][K])
    u16* poutB = pinB  + 262144;
    u16* wqT   = poutB + 262144;        // [512][512] transposed
    u16* wkT   = wqT   + 262144;
    u16* wvT   = wkT   + 262144;
    u16* woT   = wvT   + 262144;
    u16* wgT   = woT   + 262144;        // [4096][512]
    u16* wdT   = wgT   + 2097152;       // [512][2048]
    u16* ag    = qb;                    // R x 2048 bf16, aliases qb..attnb (dead by then)
    u16* vtb   = (u16*)tmp_f32;         // V^T [b*8+h][64][1024], aliases tmp_f32 (dead until pout)

    dim3 tb(32, 8);

    // stats + weight prep
    gn_stats<<<128, 256, 0, stream>>>(x, stats);
    conv_bf16<<<256, 256, 0, stream>>>(pin_w,  pinB,  262144);
    conv_bf16<<<256, 256, 0, stream>>>(pout_w, poutB, 262144);
    convT_bf16<<<dim3(16, 16),  tb, 0, stream>>>(wq, wqT, 512, 512);
    convT_bf16<<<dim3(16, 16),  tb, 0, stream>>>(wk, wkT, 512, 512);
    convT_bf16<<<dim3(16, 16),  tb, 0, stream>>>(wv, wvT, 512, 512);
    convT_bf16<<<dim3(16, 16),  tb, 0, stream>>>(wo, woT, 512, 512);
    convT_bf16<<<dim3(128, 16), tb, 0, stream>>>(wg, wgT, 512, 4096);
    convT_bf16<<<dim3(16, 64),  tb, 0, stream>>>(wd, wdT, 2048, 512);

    // h = GN(x) transposed -> Xb (bf16)
    gn_apply_t_bf<<<dim3(32, 16, 16), tb, 0, stream>>>(x, stats, gn_w, gn_b, Xb);

    // t = h @ pin_w^T + pin_b -> t_f32
    mfma_gemm<1><<<dim3(4, 128), 256, 0, stream>>>(Xb, pinB, pin_b, t_f32, nullptr, 512, 512);
    // tn = ln1(t) -> Xb
    layer_norm_rows_bf<<<16384, 256, 0, stream>>>(t_f32, ln1_w, ln1_b, Xb);
    // q, k, v (bf16, coalesced)
    mfma_gemm<0><<<dim3(4, 128), 256, 0, stream>>>(Xb, wqT, nullptr, nullptr, qb, 512, 512);
    mfma_gemm<0><<<dim3(4, 128), 256, 0, stream>>>(Xb, wkT, nullptr, nullptr, kb, 512, 512);
    mfma_gemm<0><<<dim3(4, 128), 256, 0, stream>>>(Xb, wvT, nullptr, nullptr, vb, 512, 512);
    // per-head V transpose -> vtb
    vtrans<<<dim3(16, 8, 16), 256, 0, stream>>>(vb, vtb);
    // attention (MFMA) -> attnb (bf16)
    flash_attn_mfma<<<dim3(16, 8, 16), 256, 0, stream>>>(qb, kb, vtb, attnb);
    // t += attn @ wo + bo (in-place on t_f32)
    mfma_gemm<2><<<dim3(4, 128), 256, 0, stream>>>(attnb, woT, bo, t_f32, nullptr, 512, 512);
    // tn3 = ln3(t) -> Xb
    layer_norm_rows_bf<<<16384, 256, 0, stream>>>(t_f32, ln3_w, ln3_b, Xb);
    // ag = a * gelu(g) (bf16), aliases q/k/v/attn space
    geglu_mfma<<<dim3(32, 128), 256, 0, stream>>>(Xb, wgT, bg, ag);
    // t += ag @ wd + bd (in-place), plus bf16 copy of new t -> Xb
    mfma_gemm<3><<<dim3(4, 128), 256, 0, stream>>>(ag, wdT, bd, t_f32, Xb, 2048, 512);
    // tmp = t @ pout_w^T + pout_b -> tmp_f32
    mfma_gemm<1><<<dim3(4, 128), 256, 0, stream>>>(Xb, poutB, pout_b, tmp_f32, nullptr, 512, 512);
    // out = tmp^T + x
    final_out<<<dim3(32, 16, 16), tb, 0, stream>>>(tmp_f32, x, out);
}

// Round 14
// 555.787 us; speedup vs baseline: 1.0269x; 1.0269x over previous
//
#include <hip/hip_runtime.h>
#include <hip/hip_bf16.h>
#include <math.h>

typedef unsigned short u16;
typedef __attribute__((ext_vector_type(8))) short bf16x8;
typedef __attribute__((ext_vector_type(4))) float f32x4;

#define Bb 16
#define Cch 512
#define Ss 1024
#define NHh 8
#define DHh 64
#define CPG 64
#define EPSV 1e-5f
#define R_TOTAL (Bb*Ss)   // 16384

__device__ inline u16 f2bf(float f) {
    unsigned int u = __float_as_uint(f);
    unsigned int r = (u + 0x7fffu + ((u >> 16) & 1u)) >> 16;
    return (u16)r;
}

// swizzled LDS offset (u16 units): row-stride 64, 16B chunk XOR'd by row&7
__device__ inline int swz(int row, int chunk) {
    return row * 64 + ((chunk ^ (row & 7)) * 8);
}

// async global->LDS, 16B per lane, dest = wave-uniform base + lane*16
__device__ inline void gld16(const u16* g, u16* l) {
    __builtin_amdgcn_global_load_lds(
        (const __attribute__((address_space(1))) void*)g,
        (__attribute__((address_space(3))) void*)l,
        16, 0, 0);
}

// ---------------- GroupNorm stats ----------------
__global__ __launch_bounds__(256) void gn_stats(const float* __restrict__ x,
                                                float* __restrict__ stats) {
    int bg = blockIdx.x;
    int b = bg >> 3, g = bg & 7;
    const float* base = x + ((size_t)b * Cch + (size_t)g * CPG) * Ss;
    float s = 0.f, ss = 0.f;
    for (int i = threadIdx.x; i < CPG * Ss; i += 256) {
        float v = base[i];
        s += v; ss += v * v;
    }
    for (int o = 32; o > 0; o >>= 1) { s += __shfl_down(s, o); ss += __shfl_down(ss, o); }
    __shared__ float red[2][4];
    int wid = threadIdx.x >> 6, lane = threadIdx.x & 63;
    if (lane == 0) { red[0][wid] = s; red[1][wid] = ss; }
    __syncthreads();
    if (threadIdx.x == 0) {
        float S1 = red[0][0] + red[0][1] + red[0][2] + red[0][3];
        float S2 = red[1][0] + red[1][1] + red[1][2] + red[1][3];
        const float inv_n = 1.0f / (CPG * Ss);
        float mu = S1 * inv_n;
        float var = S2 * inv_n - mu * mu;
        stats[bg * 2]     = mu;
        stats[bg * 2 + 1] = rsqrtf(var + EPSV);
    }
}

// ---------------- GroupNorm apply + transpose -> bf16 (B,S,C) ----------------
__global__ __launch_bounds__(256) void gn_apply_t_bf(const float* __restrict__ x,
                                                     const float* __restrict__ stats,
                                                     const float* __restrict__ gw,
                                                     const float* __restrict__ gb,
                                                     u16* __restrict__ ht) {
    __shared__ float tile[32][33];
    int b  = blockIdx.z;
    int c0 = blockIdx.y * 32;
    int s0 = blockIdx.x * 32;
    int tx = threadIdx.x, ty = threadIdx.y;
#pragma unroll
    for (int i = 0; i < 4; i++) {
        int c = c0 + ty + i * 8;
        int g = c >> 6;
        float mu = stats[(b * 8 + g) * 2];
        float rs = stats[(b * 8 + g) * 2 + 1];
        float v = x[((size_t)b * Cch + c) * Ss + s0 + tx];
        tile[ty + i * 8][tx] = (v - mu) * rs * gw[c] + gb[c];
    }
    __syncthreads();
#pragma unroll
    for (int i = 0; i < 4; i++) {
        int s = s0 + ty + i * 8;
        ht[((size_t)b * Ss + s) * Cch + c0 + tx] = f2bf(tile[tx][ty + i * 8]);
    }
}

// ---------------- fp32 -> bf16 straight convert ----------------
__global__ __launch_bounds__(256) void conv_bf16(const float* __restrict__ in,
                                                 u16* __restrict__ outp, int n) {
    for (int i = blockIdx.x * 256 + threadIdx.x; i < n; i += gridDim.x * 256)
        outp[i] = f2bf(in[i]);
}

// ---------------- transpose + convert: in (R x C) fp32 -> out (C x R) bf16 ----------------
__global__ __launch_bounds__(256) void convT_bf16(const float* __restrict__ in,
                                                  u16* __restrict__ outp, int R, int C) {
    __shared__ float tile[32][33];
    int c0 = blockIdx.x * 32, r0 = blockIdx.y * 32;
    int tx = threadIdx.x, ty = threadIdx.y;
#pragma unroll
    for (int i = 0; i < 4; i++)
        tile[ty + i * 8][tx] = in[(size_t)(r0 + ty + i * 8) * C + c0 + tx];
    __syncthreads();
#pragma unroll
    for (int i = 0; i < 4; i++)
        outp[(size_t)(c0 + ty + i * 8) * R + r0 + tx] = f2bf(tile[tx][ty + i * 8]);
}

// ---------------- per-head V transpose: vb [b][s][512] -> vt [(b*8+h)][64][1024] ----------
__global__ __launch_bounds__(256) void vtrans(const u16* __restrict__ in,
                                              u16* __restrict__ outp) {
    __shared__ u16 tile[64][66];
    int s0 = blockIdx.x * 64, h = blockIdx.y, b = blockIdx.z;
    const u16* src = in + ((size_t)b * Ss + s0) * Cch + h * 64;
    int r = threadIdx.x >> 3, c8 = (threadIdx.x & 7) * 8;
#pragma unroll
    for (int p = 0; p < 2; p++) {
        int rr = r + p * 32;
        *(int4*)&tile[rr][c8] = *(const int4*)&src[(size_t)rr * Cch + c8];
    }
    __syncthreads();
    u16* dst = outp + ((size_t)(b * 8 + h) * 64) * Ss + s0;
#pragma unroll
    for (int p = 0; p < 2; p++) {
        int d = r + p * 32;
        u16 vals[8];
#pragma unroll
        for (int e = 0; e < 8; e++) vals[e] = tile[c8 + e][d];
        *(int4*)&dst[(size_t)d * Ss + c8] = *(int4*)vals;
    }
}

// ---------------- LayerNorm rows (fp32 in, bf16 out) ----------------
__global__ __launch_bounds__(256) void layer_norm_rows_bf(const float* __restrict__ in,
                                                          const float* __restrict__ w,
                                                          const float* __restrict__ bb,
                                                          u16* __restrict__ outp) {
    int row = blockIdx.x;
    const float* p = in + (size_t)row * Cch;
    float v0 = p[threadIdx.x], v1 = p[threadIdx.x + 256];
    float s = v0 + v1, ss = v0 * v0 + v1 * v1;
    for (int o = 32; o > 0; o >>= 1) { s += __shfl_down(s, o); ss += __shfl_down(ss, o); }
    __shared__ float red[2][4];
    __shared__ float mu_s, rs_s;
    int wid = threadIdx.x >> 6, lane = threadIdx.x & 63;
    if (lane == 0) { red[0][wid] = s; red[1][wid] = ss; }
    __syncthreads();
    if (threadIdx.x == 0) {
        float S1 = red[0][0] + red[0][1] + red[0][2] + red[0][3];
        float S2 = red[1][0] + red[1][1] + red[1][2] + red[1][3];
        float mu = S1 * (1.0f / Cch);
        float var = S2 * (1.0f / Cch) - mu * mu;
        mu_s = mu; rs_s = rsqrtf(var + EPSV);
    }
    __syncthreads();
    float mu = mu_s, rs = rs_s;
    outp[(size_t)row * Cch + threadIdx.x]       = f2bf((v0 - mu) * rs * w[threadIdx.x] + bb[threadIdx.x]);
    outp[(size_t)row * Cch + threadIdx.x + 256] = f2bf((v1 - mu) * rs * w[threadIdx.x + 256] + bb[threadIdx.x + 256]);
}

// ---------------- MFMA GEMM: out(MxN) = A(MxK bf16) @ Bt(NxK bf16)^T ----------------
// 128x128 tile, BK=32, 256 thr = 4 waves (2x2). Staging via global_load_lds width-16.
// EPI: 0 = store bf16; 1 = fp32 +bias; 2 = fp32 +bias+res(inplace); 3 = EPI2 + bf16 copy.
template<int EPI>
__global__ __launch_bounds__(256) void mfma_gemm(const u16* __restrict__ A,
                                                 const u16* __restrict__ Bt,
                                                 const float* __restrict__ bias,
                                                 float* __restrict__ fout,
                                                 u16* __restrict__ outb,
                                                 int K, int N) {
    __shared__ u16 As[128 * 32];
    __shared__ u16 Bs[128 * 32];
    int tid = threadIdx.x;
    int m0 = blockIdx.y * 128, n0 = blockIdx.x * 128;
    int wave = tid >> 6, lane = tid & 63;
    int wr = wave >> 1, wc = wave & 1;
    int l15 = lane & 15, l4 = lane >> 4;

    f32x4 zero4 = {0.f, 0.f, 0.f, 0.f};
    f32x4 acc[4][4];
#pragma unroll
    for (int i = 0; i < 4; i++)
#pragma unroll
        for (int j = 0; j < 4; j++) acc[i][j] = zero4;

    int gr = lane >> 2, gk = (lane & 3) * 8;
    const u16* ga = A  + (size_t)(m0 + wave * 32 + gr) * K + gk;
    const u16* gb = Bt + (size_t)(n0 + wave * 32 + gr) * K + gk;
    u16* lA0 = As + wave * 1024;
    u16* lA1 = As + wave * 1024 + 512;
    u16* lB0 = Bs + wave * 1024;
    u16* lB1 = Bs + wave * 1024 + 512;

    for (int kt = 0; kt < K; kt += 32) {
        __syncthreads();
        gld16(ga + kt,                 lA0);
        gld16(ga + (size_t)16 * K + kt, lA1);
        gld16(gb + kt,                 lB0);
        gld16(gb + (size_t)16 * K + kt, lB1);
        __syncthreads();
        bf16x8 af[4], bfr[4];
#pragma unroll
        for (int mi = 0; mi < 4; mi++)
            af[mi] = *(const bf16x8*)&As[(wr * 64 + mi * 16 + l15) * 32 + l4 * 8];
#pragma unroll
        for (int nj = 0; nj < 4; nj++)
            bfr[nj] = *(const bf16x8*)&Bs[(wc * 64 + nj * 16 + l15) * 32 + l4 * 8];
#pragma unroll
        for (int mi = 0; mi < 4; mi++)
#pragma unroll
            for (int nj = 0; nj < 4; nj++)
                acc[mi][nj] = __builtin_amdgcn_mfma_f32_16x16x32_bf16(af[mi], bfr[nj], acc[mi][nj], 0, 0, 0);
    }

#pragma unroll
    for (int mi = 0; mi < 4; mi++)
#pragma unroll
        for (int nj = 0; nj < 4; nj++)
#pragma unroll
            for (int r = 0; r < 4; r++) {
                int row = m0 + wr * 64 + mi * 16 + l4 * 4 + r;
                int col = n0 + wc * 64 + nj * 16 + l15;
                float v = acc[mi][nj][r];
                if constexpr (EPI == 0) {
                    outb[(size_t)row * N + col] = f2bf(v);
                } else {
                    v += bias[col];
                    if constexpr (EPI >= 2) v += fout[(size_t)row * N + col];
                    fout[(size_t)row * N + col] = v;
                    if constexpr (EPI == 3) outb[(size_t)row * N + col] = f2bf(v);
                }
            }
}

// ---------------- GEGLU MFMA: both halves of tn3 @ wg, fused exact GELU, bf16 out --------
__global__ __launch_bounds__(256) void geglu_mfma(const u16* __restrict__ A,
                                                  const u16* __restrict__ WgT,  // [4096][512]
                                                  const float* __restrict__ bg,
                                                  u16* __restrict__ ag) {
    __shared__ u16 As[128 * 32];
    __shared__ u16 Bs1[64 * 32];
    __shared__ u16 Bs2[64 * 32];
    const int K = 512;
    int tid = threadIdx.x;
    int m0 = blockIdx.y * 128, n0 = blockIdx.x * 64;
    int wave = tid >> 6, lane = tid & 63;
    int wr = wave >> 1, wc = wave & 1;
    int l15 = lane & 15, l4 = lane >> 4;

    f32x4 zero4 = {0.f, 0.f, 0.f, 0.f};
    f32x4 accA[4][2], accG[4][2];
#pragma unroll
    for (int i = 0; i < 4; i++) { accA[i][0] = zero4; accA[i][1] = zero4; accG[i][0] = zero4; accG[i][1] = zero4; }

    int gr = lane >> 2, gk = (lane & 3) * 8;
    const u16* ga  = A   + (size_t)(m0 + wave * 32 + gr) * K + gk;
    const u16* gb1 = WgT + (size_t)(n0 + wave * 16 + gr) * K + gk;
    const u16* gb2 = WgT + (size_t)(2048 + n0 + wave * 16 + gr) * K + gk;
    u16* lA0 = As  + wave * 1024;
    u16* lA1 = As  + wave * 1024 + 512;
    u16* lB1 = Bs1 + wave * 512;
    u16* lB2 = Bs2 + wave * 512;

    for (int kt = 0; kt < K; kt += 32) {
        __syncthreads();
        gld16(ga + kt,                 lA0);
        gld16(ga + (size_t)16 * K + kt, lA1);
        gld16(gb1 + kt,                lB1);
        gld16(gb2 + kt,                lB2);
        __syncthreads();
        bf16x8 af[4], b1[2], b2[2];
#pragma unroll
        for (int mi = 0; mi < 4; mi++)
            af[mi] = *(const bf16x8*)&As[(wr * 64 + mi * 16 + l15) * 32 + l4 * 8];
#pragma unroll
        for (int nj = 0; nj < 2; nj++) {
            b1[nj] = *(const bf16x8*)&Bs1[(wc * 32 + nj * 16 + l15) * 32 + l4 * 8];
            b2[nj] = *(const bf16x8*)&Bs2[(wc * 32 + nj * 16 + l15) * 32 + l4 * 8];
        }
#pragma unroll
        for (int mi = 0; mi < 4; mi++)
#pragma unroll
            for (int nj = 0; nj < 2; nj++) {
                accA[mi][nj] = __builtin_amdgcn_mfma_f32_16x16x32_bf16(af[mi], b1[nj], accA[mi][nj], 0, 0, 0);
                accG[mi][nj] = __builtin_amdgcn_mfma_f32_16x16x32_bf16(af[mi], b2[nj], accG[mi][nj], 0, 0, 0);
            }
    }

#pragma unroll
    for (int mi = 0; mi < 4; mi++)
#pragma unroll
        for (int nj = 0; nj < 2; nj++)
#pragma unroll
            for (int r = 0; r < 4; r++) {
                int row = m0 + wr * 64 + mi * 16 + l4 * 4 + r;
                int col = n0 + wc * 32 + nj * 16 + l15;
                float a = accA[mi][nj][r] + bg[col];
                float g = accG[mi][nj][r] + bg[2048 + col];
                float ge = 0.5f * g * (1.0f + erff(g * 0.70710678118654752f));
                ag[(size_t)row * 2048 + col] = f2bf(a * ge);
            }
}

// ---------------- MFMA flash attention (XOR-swizzled LDS, __expf softmax) ----------------
// Block = 256 thr (4 waves), 64 queries of one (b,h); KV tiles of 64.
// All LDS tiles: stride 64 u16 (128B), 16B chunks XOR-swizzled by row&7 ->
// fragment b128 reads spread across all bank groups (was 8-way at stride 72).
__global__ __launch_bounds__(256) void flash_attn_mfma(const u16* __restrict__ q,
                                                       const u16* __restrict__ k,
                                                       const u16* __restrict__ vt,  // [b*8+h][64][1024]
                                                       u16* __restrict__ o) {
    __shared__ u16 Qs[64 * 64];
    __shared__ u16 Ks[64 * 64];
    __shared__ u16 Vt[64 * 64];
    __shared__ u16 Ps[64 * 64];
    const int tid = threadIdx.x;
    const int h = blockIdx.y, b = blockIdx.z;
    const int q0 = blockIdx.x * 64;
    const size_t hb  = (size_t)b * Ss * Cch + (size_t)h * DHh;
    const size_t vhb = ((size_t)(b * NHh + h) * DHh) * Ss;

    const int wq = tid >> 6;
    const int lane = tid & 63;
    const int l15 = lane & 15, l4 = lane >> 4;

    // stage Q (64x64), coalesced 32B/thread, swizzled dest
    {
        int r = tid >> 2, ch = (tid & 3) * 2;
        const u16* src = q + hb + (size_t)(q0 + r) * Cch + ch * 8;
        *(int4*)&Qs[swz(r, ch)]     = *(const int4*)src;
        *(int4*)&Qs[swz(r, ch + 1)] = *(const int4*)(src + 8);
    }

    f32x4 zero4 = {0.f, 0.f, 0.f, 0.f};
    f32x4 oacc[4];
    float m_[4], l_[4];
#pragma unroll
    for (int j = 0; j < 4; j++) oacc[j] = zero4;
#pragma unroll
    for (int r = 0; r < 4; r++) { m_[r] = -1e30f; l_[r] = 0.f; }

    for (int t0 = 0; t0 < Ss; t0 += 64) {
        __syncthreads();
        {
            int r = tid >> 2, ch = (tid & 3) * 2;
            const u16* ksrc = k + hb + (size_t)(t0 + r) * Cch + ch * 8;
            *(int4*)&Ks[swz(r, ch)]     = *(const int4*)ksrc;
            *(int4*)&Ks[swz(r, ch + 1)] = *(const int4*)(ksrc + 8);
            const u16* vsrc = vt + vhb + (size_t)r * Ss + t0 + ch * 8;
            *(int4*)&Vt[swz(r, ch)]     = *(const int4*)vsrc;
            *(int4*)&Vt[swz(r, ch + 1)] = *(const int4*)(vsrc + 8);
        }
        __syncthreads();

        // QK^T: wave's 16 q-rows x 64 t-cols
        f32x4 sacc[4];
#pragma unroll
        for (int j = 0; j < 4; j++) sacc[j] = zero4;
#pragma unroll
        for (int ks = 0; ks < 2; ks++) {
            bf16x8 aq = *(const bf16x8*)&Qs[swz(wq * 16 + l15, ks * 4 + l4)];
#pragma unroll
            for (int j = 0; j < 4; j++) {
                bf16x8 bk = *(const bf16x8*)&Ks[swz(j * 16 + l15, ks * 4 + l4)];
                sacc[j] = __builtin_amdgcn_mfma_f32_16x16x32_bf16(aq, bk, sacc[j], 0, 0, 0);
            }
        }

        // online softmax: lane holds rows l4*4+r, cols l15+16j
#pragma unroll
        for (int r = 0; r < 4; r++) {
            float s0 = sacc[0][r] * 0.125f;
            float s1 = sacc[1][r] * 0.125f;
            float s2 = sacc[2][r] * 0.125f;
            float s3 = sacc[3][r] * 0.125f;
            float tm = fmaxf(fmaxf(s0, s1), fmaxf(s2, s3));
            tm = fmaxf(tm, __shfl_xor(tm, 1));
            tm = fmaxf(tm, __shfl_xor(tm, 2));
            tm = fmaxf(tm, __shfl_xor(tm, 4));
            tm = fmaxf(tm, __shfl_xor(tm, 8));
            float nm = fmaxf(m_[r], tm);
            float sc = __expf(m_[r] - nm);
            m_[r] = nm;
            float p0 = __expf(s0 - nm), p1 = __expf(s1 - nm);
            float p2 = __expf(s2 - nm), p3 = __expf(s3 - nm);
            int row = wq * 16 + l4 * 4 + r;
            int rx = row & 7, base = row * 64, wi = l15 & 7, hi = l15 >> 3;
            Ps[base + (((0 + hi) ^ rx) * 8) + wi] = f2bf(p0);
            Ps[base + (((2 + hi) ^ rx) * 8) + wi] = f2bf(p1);
            Ps[base + (((4 + hi) ^ rx) * 8) + wi] = f2bf(p2);
            Ps[base + (((6 + hi) ^ rx) * 8) + wi] = f2bf(p3);
            float rs = p0 + p1 + p2 + p3;
            rs += __shfl_xor(rs, 1);
            rs += __shfl_xor(rs, 2);
            rs += __shfl_xor(rs, 4);
            rs += __shfl_xor(rs, 8);
            l_[r] = l_[r] * sc + rs;
#pragma unroll
            for (int j = 0; j < 4; j++) oacc[j][r] *= sc;
        }

        // PV: A=Ps (own rows, same-wave dep), Bt=Vt[d][t]
#pragma unroll
        for (int ks = 0; ks < 2; ks++) {
            bf16x8 pa = *(const bf16x8*)&Ps[swz(wq * 16 + l15, ks * 4 + l4)];
#pragma unroll
            for (int j = 0; j < 4; j++) {
                bf16x8 bv = *(const bf16x8*)&Vt[swz(j * 16 + l15, ks * 4 + l4)];
                oacc[j] = __builtin_amdgcn_mfma_f32_16x16x32_bf16(pa, bv, oacc[j], 0, 0, 0);
            }
        }
    }

    // finalize: O /= l, stage via Qs (wave-private rows, swizzled), coalesced store
#pragma unroll
    for (int r = 0; r < 4; r++) {
        float inv = 1.0f / l_[r];
        int row = wq * 16 + l4 * 4 + r;
        int rx = row & 7, base = row * 64, wi = l15 & 7, hi = l15 >> 3;
        Qs[base + (((0 + hi) ^ rx) * 8) + wi] = f2bf(oacc[0][r] * inv);
        Qs[base + (((2 + hi) ^ rx) * 8) + wi] = f2bf(oacc[1][r] * inv);
        Qs[base + (((4 + hi) ^ rx) * 8) + wi] = f2bf(oacc[2][r] * inv);
        Qs[base + (((6 + hi) ^ rx) * 8) + wi] = f2bf(oacc[3][r] * inv);
    }
    __syncthreads();
    {
        int r = tid >> 2, ch = (tid & 3) * 2;
        u16* dst = o + hb + (size_t)(q0 + r) * Cch + ch * 8;
        *(int4*)dst       = *(const int4*)&Qs[swz(r, ch)];
        *(int4*)(dst + 8) = *(const int4*)&Qs[swz(r, ch + 1)];
    }
}

// ---------------- final: out(B,C,S) = tmp(B,S,C)^T + x ----------------
__global__ __launch_bounds__(256) void final_out(const float* __restrict__ tmp,
                                                 const float* __restrict__ x,
                                                 float* __restrict__ outp) {
    __shared__ float tile[32][33];
    int b = blockIdx.z, c0 = blockIdx.y * 32, s0 = blockIdx.x * 32;
    int tx = threadIdx.x, ty = threadIdx.y;
#pragma unroll
    for (int i = 0; i < 4; i++) {
        int s = s0 + ty + i * 8;
        tile[ty + i * 8][tx] = tmp[((size_t)b * Ss + s) * Cch + c0 + tx];
    }
    __syncthreads();
#pragma unroll
    for (int i = 0; i < 4; i++) {
        int c = c0 + ty + i * 8;
        size_t idx = ((size_t)b * Cch + c) * Ss + s0 + tx;
        outp[idx] = tile[tx][ty + i * 8] + x[idx];
    }
}

extern "C" void kernel_launch(void* const* d_in, const int* in_sizes, int n_in,
                              void* d_out, int out_size, void* d_ws, size_t ws_size,
                              hipStream_t stream) {
    (void)in_sizes; (void)n_in; (void)out_size; (void)ws_size;
    const float* x      = (const float*)d_in[0];
    const float* gn_w   = (const float*)d_in[1];
    const float* gn_b   = (const float*)d_in[2];
    const float* pin_w  = (const float*)d_in[3];
    const float* pin_b  = (const float*)d_in[4];
    const float* ln1_w  = (const float*)d_in[5];
    const float* ln1_b  = (const float*)d_in[6];
    const float* wq     = (const float*)d_in[7];
    const float* wk     = (const float*)d_in[8];
    const float* wv     = (const float*)d_in[9];
    const float* wo     = (const float*)d_in[10];
    const float* bo     = (const float*)d_in[11];
    const float* ln3_w  = (const float*)d_in[12];
    const float* ln3_b  = (const float*)d_in[13];
    const float* wg     = (const float*)d_in[14];
    const float* bg     = (const float*)d_in[15];
    const float* wd     = (const float*)d_in[16];
    const float* bd     = (const float*)d_in[17];
    const float* pout_w = (const float*)d_in[18];
    const float* pout_b = (const float*)d_in[19];
    float* out = (float*)d_out;

    // ---- workspace layout (bytes) ----
    char* W = (char*)d_ws;
    float* t_f32   = (float*)W;                                   // 33.55 MB
    float* tmp_f32 = (float*)(W + 33554432);                      // 33.55 MB
    u16* qb    = (u16*)(W + 67108864);                            // 16.78 MB
    u16* kb    = qb + 8388608;
    u16* vb    = kb + 8388608;
    u16* attnb = vb + 8388608;
    u16* Xb    = attnb + 8388608;                                 // 16.78 MB
    float* stats = (float*)(W + 67108864 + 5ull * 16777216);      // 1 KB
    u16* wbase = (u16*)(W + 67108864 + 5ull * 16777216 + 1024);
    u16* pinB  = wbase;                 // 512*512  (already [N][K])
    u16* poutB = pinB  + 262144;
    u16* wqT   = poutB + 262144;        // [512][512] transposed
    u16* wkT   = wqT   + 262144;
    u16* wvT   = wkT   + 262144;
    u16* woT   = wvT   + 262144;
    u16* wgT   = woT   + 262144;        // [4096][512]
    u16* wdT   = wgT   + 2097152;       // [512][2048]
    u16* ag    = qb;                    // R x 2048 bf16, aliases qb..attnb (dead by then)
    u16* vtb   = (u16*)tmp_f32;         // V^T [b*8+h][64][1024], aliases tmp_f32 (dead until pout)

    dim3 tb(32, 8);

    // stats + weight prep
    gn_stats<<<128, 256, 0, stream>>>(x, stats);
    conv_bf16<<<256, 256, 0, stream>>>(pin_w,  pinB,  262144);
    conv_bf16<<<256, 256, 0, stream>>>(pout_w, poutB, 262144);
    convT_bf16<<<dim3(16, 16),  tb, 0, stream>>>(wq, wqT, 512, 512);
    convT_bf16<<<dim3(16, 16),  tb, 0, stream>>>(wk, wkT, 512, 512);
    convT_bf16<<<dim3(16, 16),  tb, 0, stream>>>(wv, wvT, 512, 512);
    convT_bf16<<<dim3(16, 16),  tb, 0, stream>>>(wo, woT, 512, 512);
    convT_bf16<<<dim3(128, 16), tb, 0, stream>>>(wg, wgT, 512, 4096);
    convT_bf16<<<dim3(16, 64),  tb, 0, stream>>>(wd, wdT, 2048, 512);

    // h = GN(x) transposed -> Xb (bf16)
    gn_apply_t_bf<<<dim3(32, 16, 16), tb, 0, stream>>>(x, stats, gn_w, gn_b, Xb);

    // t = h @ pin_w^T + pin_b -> t_f32
    mfma_gemm<1><<<dim3(4, 128), 256, 0, stream>>>(Xb, pinB, pin_b, t_f32, nullptr, 512, 512);
    // tn = ln1(t) -> Xb
    layer_norm_rows_bf<<<16384, 256, 0, stream>>>(t_f32, ln1_w, ln1_b, Xb);
    // q, k, v (bf16, coalesced)
    mfma_gemm<0><<<dim3(4, 128), 256, 0, stream>>>(Xb, wqT, nullptr, nullptr, qb, 512, 512);
    mfma_gemm<0><<<dim3(4, 128), 256, 0, stream>>>(Xb, wkT, nullptr, nullptr, kb, 512, 512);
    mfma_gemm<0><<<dim3(4, 128), 256, 0, stream>>>(Xb, wvT, nullptr, nullptr, vb, 512, 512);
    // per-head V transpose -> vtb
    vtrans<<<dim3(16, 8, 16), 256, 0, stream>>>(vb, vtb);
    // attention (MFMA) -> attnb (bf16)
    flash_attn_mfma<<<dim3(16, 8, 16), 256, 0, stream>>>(qb, kb, vtb, attnb);
    // t += attn @ wo + bo (in-place on t_f32)
    mfma_gemm<2><<<dim3(4, 128), 256, 0, stream>>>(attnb, woT, bo, t_f32, nullptr, 512, 512);
    // tn3 = ln3(t) -> Xb
    layer_norm_rows_bf<<<16384, 256, 0, stream>>>(t_f32, ln3_w, ln3_b, Xb);
    // ag = a * gelu(g) (bf16), aliases q/k/v/attn space
    geglu_mfma<<<dim3(32, 128), 256, 0, stream>>>(Xb, wgT, bg, ag);
    // t += ag @ wd + bd (in-place), plus bf16 copy of new t -> Xb
    mfma_gemm<3><<<dim3(4, 128), 256, 0, stream>>>(ag, wdT, bd, t_f32, Xb, 2048, 512);
    // tmp = t @ pout_w^T + pout_b -> tmp_f32
    mfma_gemm<1><<<dim3(4, 128), 256, 0, stream>>>(Xb, poutB, pout_b, tmp_f32, nullptr, 512, 512);
    // out = tmp^T + x
    final_out<<<dim3(32, 16, 16), tb, 0, stream>>>(tmp_f32, x, out);
}